// Round 17
// baseline (108.620 us; speedup 1.0000x reference)
//
#include <hip/hip_runtime.h>

typedef __bf16 bf16x8 __attribute__((ext_vector_type(8)));
typedef __bf16 bf16x4 __attribute__((ext_vector_type(4)));
typedef __bf16 bf16x2 __attribute__((ext_vector_type(2)));
typedef float  f32x4  __attribute__((ext_vector_type(4)));

// CK-pattern async global->LDS (16B per lane, wave-uniform LDS base).
__device__ __forceinline__ void gload_lds16(const void* g, void* l) {
    auto gp = reinterpret_cast<const __attribute__((address_space(1))) unsigned int*>(
        reinterpret_cast<uintptr_t>(g));
    auto lp = reinterpret_cast<__attribute__((address_space(3))) unsigned int*>(
        reinterpret_cast<uintptr_t>(l));
    __builtin_amdgcn_global_load_lds(gp, lp, 16, 0, 0);
}

// Raw barriers with counted waits (T4/m201 discipline).
__device__ __forceinline__ void barrier_vm2_lgkm() {
    __builtin_amdgcn_sched_barrier(0);
    asm volatile("s_waitcnt vmcnt(2) lgkmcnt(0)" ::: "memory");
    __builtin_amdgcn_s_barrier();
    __builtin_amdgcn_sched_barrier(0);
}
__device__ __forceinline__ void barrier_vm0_lgkm() {
    __builtin_amdgcn_sched_barrier(0);
    asm volatile("s_waitcnt vmcnt(0) lgkmcnt(0)" ::: "memory");
    __builtin_amdgcn_s_barrier();
    __builtin_amdgcn_sched_barrier(0);
}

// XCD-aware swizzles: each XCD owns a contiguous band of m-rows (all
// n-blocks) so its A-stripe stays L2-resident.  All bijective (grid % 8 == 0).
__device__ __forceinline__ void xcd_remap512(int lin, int& bx, int& by) {
    const int wgid = (lin & 7) * 64 + (lin >> 3);   // 8 n x 64 m
    bx = wgid & 7;
    by = wgid >> 3;
}
__device__ __forceinline__ void xcd_remap1024(int lin, int& bx, int& by) {
    const int wgid = (lin & 7) * 128 + (lin >> 3);  // 8 n x 128 m
    bx = wgid & 7;
    by = wgid >> 3;
}

// ---------------------------------------------------------------------------
// Merged prep (1 launch): Wq/Wo transposes + addresses->bf16 + query->bf16.
// ---------------------------------------------------------------------------
__global__ __launch_bounds__(256) void prep_all(
    const float* __restrict__ Wq, const float* __restrict__ Wo,
    const float* __restrict__ adr, const float* __restrict__ query,
    __bf16* __restrict__ WqT, __bf16* __restrict__ WoT,
    __bf16* __restrict__ adrb, __bf16* __restrict__ Qbf)
{
    __shared__ float tile[32][33];
    const int bid = blockIdx.x, tid = threadIdx.x;

    if (bid < 1024) {
        const float* src; __bf16* dst; int R, C, r0, c0;
        if (bid < 512) {             // Wq [1024][512] -> WqT [512][1024]
            src = Wq; dst = WqT; R = 1024; C = 512;
            c0 = (bid & 15) * 32; r0 = (bid >> 4) * 32;
        } else {                     // Wo [512][1024] -> WoT [1024][512]
            const int b = bid - 512;
            src = Wo; dst = WoT; R = 512; C = 1024;
            c0 = (b & 31) * 32; r0 = (b >> 5) * 32;
        }
        const int tx = tid & 31, ty = tid >> 5;
        #pragma unroll
        for (int i = ty; i < 32; i += 8)
            tile[i][tx] = src[(size_t)(r0 + i) * C + c0 + tx];
        __syncthreads();
        #pragma unroll
        for (int i = ty; i < 32; i += 8)
            dst[(size_t)(c0 + i) * R + r0 + tx] = (__bf16)tile[tx][i];
    } else if (bid < 1028) {         // addresses [128][64] f32 -> bf16
        const int i = (bid - 1024) * 256 + tid;
        f32x4 a = ((const f32x4*)adr)[2 * i];
        f32x4 b = ((const f32x4*)adr)[2 * i + 1];
        bf16x8 o;
        #pragma unroll
        for (int j = 0; j < 4; ++j) { o[j] = (__bf16)a[j]; o[4 + j] = (__bf16)b[j]; }
        ((bf16x8*)adrb)[i] = o;
    } else {                         // query [8192][1024] f32 -> bf16
        const int i = (bid - 1028) * 256 + tid;
        f32x4 a = ((const f32x4*)query)[2 * i];
        f32x4 b = ((const f32x4*)query)[2 * i + 1];
        bf16x8 o;
        #pragma unroll
        for (int j = 0; j < 4; ++j) { o[j] = (__bf16)a[j]; o[4 + j] = (__bf16)b[j]; }
        ((bf16x8*)Qbf)[i] = o;
    }
}

// ---------------------------------------------------------------------------
// Q-proj GEMM — 3-buffer counted-vmcnt, now BM=64 BN=64, 256 threads
// (4 waves, 2m x 2n, wave tile 32x32), grid 1024 -> 4 blocks/CU so
// co-resident blocks fill each other's barrier stalls (m114 overlap).
// Per wave: 1 A + 1 B gload per step (uniform) -> same vmcnt(2) discipline.
// ---------------------------------------------------------------------------
__global__ __launch_bounds__(256) void gemm_qproj(
    const __bf16* __restrict__ A, const __bf16* __restrict__ BT,
    const float* __restrict__ bias, __bf16* __restrict__ Out,
    int M, int N, int K)
{
    __shared__ __bf16 As[3][64][32];
    __shared__ __bf16 Bs[3][64][32];

    const int tid = threadIdx.x, lane = tid & 63, w = tid >> 6;
    const int wm = w >> 1, wn = w & 1;          // 2 x 2 wave grid
    int bx, by;
    xcd_remap1024(blockIdx.x + 8 * blockIdx.y, bx, by);
    const int m0 = by * 64, n0 = bx * 64;
    const int r = lane & 15, g = lane >> 4;

    const int srow = lane >> 2;
    const int scol = (lane & 3) * 8;
    const __bf16* gA = A  + (size_t)(m0 + 16 * w + srow) * K + scol;
    const __bf16* gB = BT + (size_t)(n0 + 16 * w + srow) * K + scol;

    f32x4 acc[2][2];
    const f32x4 zero = {0.f, 0.f, 0.f, 0.f};
    #pragma unroll
    for (int mi = 0; mi < 2; ++mi)
        #pragma unroll
        for (int ni = 0; ni < 2; ++ni) acc[mi][ni] = zero;

    const int NT = K / 32;                              // 32

    gload_lds16(gA,      &As[0][16 * w][0]);
    gload_lds16(gB,      &Bs[0][16 * w][0]);
    gload_lds16(gA + 32, &As[1][16 * w][0]);
    gload_lds16(gB + 32, &Bs[1][16 * w][0]);
    __builtin_amdgcn_sched_barrier(0);
    asm volatile("s_waitcnt vmcnt(2)" ::: "memory");
    __builtin_amdgcn_s_barrier();
    __builtin_amdgcn_sched_barrier(0);

    int buf = 0;
    for (int t = 0; t < NT; ++t) {
        if (t + 2 < NT) {
            const int nb = (buf + 2 >= 3) ? buf - 1 : buf + 2;
            gload_lds16(gA + (t + 2) * 32, &As[nb][16 * w][0]);
            gload_lds16(gB + (t + 2) * 32, &Bs[nb][16 * w][0]);
        }
        bf16x8 af[2], bfr[2];
        #pragma unroll
        for (int mi = 0; mi < 2; ++mi)
            af[mi] = *(const bf16x8*)&As[buf][wm * 32 + mi * 16 + r][g * 8];
        #pragma unroll
        for (int ni = 0; ni < 2; ++ni)
            bfr[ni] = *(const bf16x8*)&Bs[buf][wn * 32 + ni * 16 + r][g * 8];
        #pragma unroll
        for (int mi = 0; mi < 2; ++mi)
            #pragma unroll
            for (int ni = 0; ni < 2; ++ni)
                acc[mi][ni] = __builtin_amdgcn_mfma_f32_16x16x32_bf16(
                    af[mi], bfr[ni], acc[mi][ni], 0, 0, 0);
        if (t + 1 < NT) {
            if (t + 2 < NT) barrier_vm2_lgkm();
            else            barrier_vm0_lgkm();
        }
        buf = (buf + 1 >= 3) ? 0 : buf + 1;
    }

    const int orow = m0 + wm * 32 + g * 4;
    const int ocol = n0 + wn * 32 + r;
    #pragma unroll
    for (int ni = 0; ni < 2; ++ni) {
        const float bb = bias[ocol + ni * 16];
        #pragma unroll
        for (int mi = 0; mi < 2; ++mi) {
            #pragma unroll
            for (int q = 0; q < 4; ++q) {
                float v = fmaxf(acc[mi][ni][q] + bb, 0.f);
                Out[(size_t)(orow + mi * 16 + q) * N + ocol + ni * 16] = (__bf16)v;
            }
        }
    }
}

// ---------------------------------------------------------------------------
// Out-proj GEMM (r13/r14 3-buffer counted-vmcnt — kept byte-identical).
// ---------------------------------------------------------------------------
__global__ __launch_bounds__(512) void gemm_oproj(
    const __bf16* __restrict__ A, const __bf16* __restrict__ BT,
    const float* __restrict__ bias, float* __restrict__ Out,
    int M, int N, int K)
{
    __shared__ __bf16 As[3][128][32];
    __shared__ __bf16 Bs[3][128][32];

    const int tid = threadIdx.x, lane = tid & 63, w = tid >> 6;
    const int wm = w >> 1, wn = w & 1;          // 4 x 2 wave grid
    int bx, by;
    xcd_remap512(blockIdx.x + 8 * blockIdx.y, bx, by);
    const int m0 = by * 128, n0 = bx * 128;
    const int r = lane & 15, g = lane >> 4;

    const int srow = lane >> 2;
    const int scol = (lane & 3) * 8;
    const __bf16* gA = A  + (size_t)(m0 + 16 * w + srow) * K + scol;
    const __bf16* gB = BT + (size_t)(n0 + 16 * w + srow) * K + scol;

    f32x4 acc[2][4];
    const f32x4 zero = {0.f, 0.f, 0.f, 0.f};
    #pragma unroll
    for (int mi = 0; mi < 2; ++mi)
        #pragma unroll
        for (int ni = 0; ni < 4; ++ni) acc[mi][ni] = zero;

    const int NT = K / 32;                              // 16

    gload_lds16(gA,      &As[0][16 * w][0]);
    gload_lds16(gB,      &Bs[0][16 * w][0]);
    gload_lds16(gA + 32, &As[1][16 * w][0]);
    gload_lds16(gB + 32, &Bs[1][16 * w][0]);
    __builtin_amdgcn_sched_barrier(0);
    asm volatile("s_waitcnt vmcnt(2)" ::: "memory");
    __builtin_amdgcn_s_barrier();
    __builtin_amdgcn_sched_barrier(0);

    int buf = 0;
    for (int t = 0; t < NT; ++t) {
        if (t + 2 < NT) {
            const int nb = (buf + 2 >= 3) ? buf - 1 : buf + 2;
            gload_lds16(gA + (t + 2) * 32, &As[nb][16 * w][0]);
            gload_lds16(gB + (t + 2) * 32, &Bs[nb][16 * w][0]);
        }
        bf16x8 af[2], bfr[4];
        #pragma unroll
        for (int mi = 0; mi < 2; ++mi)
            af[mi] = *(const bf16x8*)&As[buf][wm * 32 + mi * 16 + r][g * 8];
        #pragma unroll
        for (int ni = 0; ni < 4; ++ni)
            bfr[ni] = *(const bf16x8*)&Bs[buf][wn * 64 + ni * 16 + r][g * 8];
        #pragma unroll
        for (int mi = 0; mi < 2; ++mi)
            #pragma unroll
            for (int ni = 0; ni < 4; ++ni)
                acc[mi][ni] = __builtin_amdgcn_mfma_f32_16x16x32_bf16(
                    af[mi], bfr[ni], acc[mi][ni], 0, 0, 0);
        if (t + 1 < NT) {
            if (t + 2 < NT) barrier_vm2_lgkm();
            else            barrier_vm0_lgkm();
        }
        buf = (buf + 1 >= 3) ? 0 : buf + 1;
    }

    const int orow = m0 + wm * 32 + g * 4;
    const int ocol = n0 + wn * 64 + r;
    #pragma unroll
    for (int ni = 0; ni < 4; ++ni) {
        const float bb = bias[ocol + ni * 16];
        #pragma unroll
        for (int mi = 0; mi < 2; ++mi) {
            #pragma unroll
            for (int q = 0; q < 4; ++q) {
                Out[(size_t)(orow + mi * 16 + q) * N + ocol + ni * 16]
                    = acc[mi][ni][q] + bb;
            }
        }
    }
}

// ---------------------------------------------------------------------------
// Fused memory attention (MFMA) — at HBM floor (43.7 µs, r8).  Do not touch.
// ---------------------------------------------------------------------------
__device__ __forceinline__ int kbyte(int m, int e) {
    return m * 128 + ((((e >> 3) ^ (m & 7))) << 4) + (e & 7) * 2;
}

__global__ void memory_attn_mfma(
    const __bf16* __restrict__ Q,      // [N][512] bf16 (relu'd q proj)
    const float*  __restrict__ mem,    // [N][128][64] f32
    const __bf16* __restrict__ adrb,   // [128][64] bf16
    __bf16* __restrict__ attn)         // [N][512] bf16
{
    __shared__ __align__(16) unsigned char kbuf[4][4096];
    __shared__ __align__(16) unsigned char tbuf[4][5120];
    __shared__ float denl[4][8];

    const int tid = threadIdx.x, lane = tid & 63, w = tid >> 6;
    const int n = blockIdx.x * 4 + w;
    const int v = lane & 15, g = lane >> 4;

    unsigned char* kb = kbuf[w];
    unsigned char* tb = tbuf[w];

    const __bf16* qp = Q + (size_t)n * 512 + v * 64 + 8 * g;
    const bf16x8 qf0 = *(const bf16x8*)(qp);
    const bf16x8 qf1 = *(const bf16x8*)(qp + 32);

    f32x4 acc[4];
    const f32x4 zero = {0.f, 0.f, 0.f, 0.f};
    #pragma unroll
    for (int nb = 0; nb < 4; ++nb) acc[nb] = zero;
    float psum = 0.f;

    for (int c = 0; c < 4; ++c) {
        const int mb = c * 32;
        #pragma unroll
        for (int i = 0; i < 4; ++i) {
            const int mo = 8 * i + 2 * g;
            const int e  = 4 * v;
            const float* pm = mem + (((size_t)n * 128 + mb + mo) * 64 + e);
            const f32x4 m0 = *(const f32x4*)pm;
            const f32x4 m1 = *(const f32x4*)(pm + 64);
            const bf16x4 a0 = *(const bf16x4*)(adrb + (size_t)(mb + mo) * 64 + e);
            const bf16x4 a1 = *(const bf16x4*)(adrb + (size_t)(mb + mo + 1) * 64 + e);
            bf16x4 k0, k1;
            #pragma unroll
            for (int j = 0; j < 4; ++j) {
                k0[j] = (__bf16)fmaxf(m0[j] + (float)a0[j], 0.f);
                k1[j] = (__bf16)fmaxf(m1[j] + (float)a1[j], 0.f);
            }
            *(bf16x4*)(kb + kbyte(mo,     e)) = k0;
            *(bf16x4*)(kb + kbyte(mo + 1, e)) = k1;
            const int kap = 8 * ((mo >> 2) & 3) + 4 * (mo >> 4) + (mo & 3);
            #pragma unroll
            for (int j2 = 0; j2 < 4; ++j2) {
                bf16x2 p = { (__bf16)m0[j2], (__bf16)m1[j2] };
                *(bf16x2*)(tb + (size_t)(e + j2) * 80 + kap * 2) = p;
            }
        }

        f32x4 sA0 = zero, sA1 = zero;
        {
            const bf16x8 a00 = *(const bf16x8*)(kb + kbyte(v,      8 * g));
            const bf16x8 a01 = *(const bf16x8*)(kb + kbyte(v,      32 + 8 * g));
            const bf16x8 a10 = *(const bf16x8*)(kb + kbyte(v + 16, 8 * g));
            const bf16x8 a11 = *(const bf16x8*)(kb + kbyte(v + 16, 32 + 8 * g));
            sA0 = __builtin_amdgcn_mfma_f32_16x16x32_bf16(a00, qf0, sA0, 0, 0, 0);
            sA0 = __builtin_amdgcn_mfma_f32_16x16x32_bf16(a01, qf1, sA0, 0, 0, 0);
            sA1 = __builtin_amdgcn_mfma_f32_16x16x32_bf16(a10, qf0, sA1, 0, 0, 0);
            sA1 = __builtin_amdgcn_mfma_f32_16x16x32_bf16(a11, qf1, sA1, 0, 0, 0);
        }
        psum += sA0[0] + sA0[1] + sA0[2] + sA0[3]
              + sA1[0] + sA1[1] + sA1[2] + sA1[3];

        bf16x8 pa;
        #pragma unroll
        for (int q = 0; q < 4; ++q) {
            pa[q]     = (__bf16)sA0[q];
            pa[4 + q] = (__bf16)sA1[q];
        }

        #pragma unroll
        for (int nb = 0; nb < 4; ++nb) {
            const bf16x8 bf = *(const bf16x8*)(tb + (size_t)(16 * nb + v) * 80 + 16 * g);
            acc[nb] = __builtin_amdgcn_mfma_f32_16x16x32_bf16(pa, bf, acc[nb], 0, 0, 0);
        }
    }

    psum += __shfl_xor(psum, 16);
    psum += __shfl_xor(psum, 32);
    if (lane < 8) denl[w][lane] = psum;

    if (g < 2) {
        const f32x4 d4 = *(const f32x4*)&denl[w][4 * g];
        float inv[4];
        #pragma unroll
        for (int q = 0; q < 4; ++q) inv[q] = 1.f / (d4[q] + 1e-5f);
        #pragma unroll
        for (int nb = 0; nb < 4; ++nb) {
            #pragma unroll
            for (int q = 0; q < 4; ++q) {
                attn[(size_t)n * 512 + (4 * g + q) * 64 + 16 * nb + v] =
                    (__bf16)(acc[nb][q] * inv[q]);
            }
        }
    }
}

// ---------------------------------------------------------------------------
extern "C" void kernel_launch(void* const* d_in, const int* in_sizes, int n_in,
                              void* d_out, int out_size, void* d_ws, size_t ws_size,
                              hipStream_t stream)
{
    const float* query     = (const float*)d_in[0];
    const float* addresses = (const float*)d_in[1];
    const float* memories  = (const float*)d_in[2];
    const float* Wq        = (const float*)d_in[3];
    const float* bq        = (const float*)d_in[4];
    const float* Wo        = (const float*)d_in[5];
    const float* bo        = (const float*)d_in[6];
    float* out = (float*)d_out;

    char* ws = (char*)d_ws;
    __bf16* WqT  = (__bf16*)(ws);                      // [512][1024]  1 MB
    __bf16* WoT  = (__bf16*)(ws + (1 << 20));          // [1024][512]  1 MB
    __bf16* Qb   = (__bf16*)(ws + (2 << 20));          // [8192][512]  8 MB
    __bf16* Ab   = (__bf16*)(ws + (10 << 20));         // [8192][512]  8 MB
    __bf16* Adrb = (__bf16*)(ws + (18 << 20));         // [128][64]    16 KB
    __bf16* Qbf  = (__bf16*)d_out;                     // [8192][1024] bf16, 16 MB
                                                       // stashed in d_out,
                                                       // overwritten by oproj

    // prep: weight transposes + addr convert + query->bf16 (one launch)
    prep_all<<<5124, 256, 0, stream>>>(Wq, Wo, addresses, query,
                                       WqT, WoT, Adrb, Qbf);

    // Q = relu(Qbf @ Wq + bq) -> bf16 [8192][512]
    // (3-buffer counted vmcnt, 64x64 tiles, 1024 blocks = 4/CU)
    gemm_qproj<<<dim3(512 / 64, 8192 / 64), 256, 0, stream>>>(
        Qbf, WqT, bq, Qb, 8192, 512, 1024);

    // fused per-token linear memory read (MFMA) -> attn bf16 [8192][512]
    memory_attn_mfma<<<dim3(8192 / 4), 256, 0, stream>>>(Qb, memories, Adrb, Ab);

    // out = attn @ Wo + bo -> f32 [8192][1024]  (3-buffer counted vmcnt)
    gemm_oproj<<<dim3(1024 / 128, 8192 / 128), 512, 0, stream>>>(
        Ab, WoT, bo, out, 8192, 1024, 512);
}

// Round 18
// 104.865 us; speedup vs baseline: 1.0358x; 1.0358x over previous
//
#include <hip/hip_runtime.h>

typedef __bf16 bf16x8 __attribute__((ext_vector_type(8)));
typedef __bf16 bf16x4 __attribute__((ext_vector_type(4)));
typedef __bf16 bf16x2 __attribute__((ext_vector_type(2)));
typedef float  f32x4  __attribute__((ext_vector_type(4)));

// CK-pattern async global->LDS (16B per lane, wave-uniform LDS base).
__device__ __forceinline__ void gload_lds16(const void* g, void* l) {
    auto gp = reinterpret_cast<const __attribute__((address_space(1))) unsigned int*>(
        reinterpret_cast<uintptr_t>(g));
    auto lp = reinterpret_cast<__attribute__((address_space(3))) unsigned int*>(
        reinterpret_cast<uintptr_t>(l));
    __builtin_amdgcn_global_load_lds(gp, lp, 16, 0, 0);
}

// Raw barriers with counted waits (T4/m201 discipline).
__device__ __forceinline__ void barrier_vm2_lgkm() {
    __builtin_amdgcn_sched_barrier(0);
    asm volatile("s_waitcnt vmcnt(2) lgkmcnt(0)" ::: "memory");
    __builtin_amdgcn_s_barrier();
    __builtin_amdgcn_sched_barrier(0);
}
__device__ __forceinline__ void barrier_vm3_lgkm() {
    __builtin_amdgcn_sched_barrier(0);
    asm volatile("s_waitcnt vmcnt(3) lgkmcnt(0)" ::: "memory");
    __builtin_amdgcn_s_barrier();
    __builtin_amdgcn_sched_barrier(0);
}
__device__ __forceinline__ void barrier_vm0_lgkm() {
    __builtin_amdgcn_sched_barrier(0);
    asm volatile("s_waitcnt vmcnt(0) lgkmcnt(0)" ::: "memory");
    __builtin_amdgcn_s_barrier();
    __builtin_amdgcn_sched_barrier(0);
}

// XCD-aware swizzle: each XCD owns a contiguous band of m-rows (all
// n-blocks) so its A-stripe stays L2-resident.  Bijective (512 % 8 == 0).
__device__ __forceinline__ void xcd_remap512(int lin, int& bx, int& by) {
    const int wgid = (lin & 7) * 64 + (lin >> 3);   // 8 n x 64 m
    bx = wgid & 7;
    by = wgid >> 3;
}

// ---------------------------------------------------------------------------
// Merged prep (1 launch): Wq/Wo transposes + addresses->bf16 + query->bf16.
// ---------------------------------------------------------------------------
__global__ __launch_bounds__(256) void prep_all(
    const float* __restrict__ Wq, const float* __restrict__ Wo,
    const float* __restrict__ adr, const float* __restrict__ query,
    __bf16* __restrict__ WqT, __bf16* __restrict__ WoT,
    __bf16* __restrict__ adrb, __bf16* __restrict__ Qbf)
{
    __shared__ float tile[32][33];
    const int bid = blockIdx.x, tid = threadIdx.x;

    if (bid < 1024) {
        const float* src; __bf16* dst; int R, C, r0, c0;
        if (bid < 512) {             // Wq [1024][512] -> WqT [512][1024]
            src = Wq; dst = WqT; R = 1024; C = 512;
            c0 = (bid & 15) * 32; r0 = (bid >> 4) * 32;
        } else {                     // Wo [512][1024] -> WoT [1024][512]
            const int b = bid - 512;
            src = Wo; dst = WoT; R = 512; C = 1024;
            c0 = (b & 31) * 32; r0 = (b >> 5) * 32;
        }
        const int tx = tid & 31, ty = tid >> 5;
        #pragma unroll
        for (int i = ty; i < 32; i += 8)
            tile[i][tx] = src[(size_t)(r0 + i) * C + c0 + tx];
        __syncthreads();
        #pragma unroll
        for (int i = ty; i < 32; i += 8)
            dst[(size_t)(c0 + i) * R + r0 + tx] = (__bf16)tile[tx][i];
    } else if (bid < 1028) {         // addresses [128][64] f32 -> bf16
        const int i = (bid - 1024) * 256 + tid;
        f32x4 a = ((const f32x4*)adr)[2 * i];
        f32x4 b = ((const f32x4*)adr)[2 * i + 1];
        bf16x8 o;
        #pragma unroll
        for (int j = 0; j < 4; ++j) { o[j] = (__bf16)a[j]; o[4 + j] = (__bf16)b[j]; }
        ((bf16x8*)adrb)[i] = o;
    } else {                         // query [8192][1024] f32 -> bf16
        const int i = (bid - 1028) * 256 + tid;
        f32x4 a = ((const f32x4*)query)[2 * i];
        f32x4 b = ((const f32x4*)query)[2 * i + 1];
        bf16x8 o;
        #pragma unroll
        for (int j = 0; j < 4; ++j) { o[j] = (__bf16)a[j]; o[4 + j] = (__bf16)b[j]; }
        ((bf16x8*)Qbf)[i] = o;
    }
}

// ---------------------------------------------------------------------------
// Q-proj GEMM — 3-buffer counted-vmcnt, BM=128 BN=64, 256 threads (4 waves
// 2m x 2n, wave tile 64x32 = r9's proven geometry), grid 512 -> 2 blocks/CU
// (oproj's occupancy) at UNCHANGED per-block tile efficiency.
// Per wave per step: 2 A-gloads + 1 B-gload (uniform) -> vmcnt(3) barriers.
// ---------------------------------------------------------------------------
__global__ __launch_bounds__(256) void gemm_qproj(
    const __bf16* __restrict__ A, const __bf16* __restrict__ BT,
    const float* __restrict__ bias, __bf16* __restrict__ Out,
    int M, int N, int K)
{
    __shared__ __bf16 As[3][128][32];
    __shared__ __bf16 Bs[3][64][32];

    const int tid = threadIdx.x, lane = tid & 63, w = tid >> 6;
    const int wm = w >> 1, wn = w & 1;          // 2 x 2 wave grid
    int bx, by;
    xcd_remap512(blockIdx.x + 8 * blockIdx.y, bx, by);
    const int m0 = by * 128, n0 = bx * 64;
    const int r = lane & 15, g = lane >> 4;

    const int srow = lane >> 2;
    const int scol = (lane & 3) * 8;
    const __bf16* gA = A  + (size_t)(m0 + 32 * w + srow) * K + scol;
    const __bf16* gB = BT + (size_t)(n0 + 16 * w + srow) * K + scol;

    f32x4 acc[4][2];
    const f32x4 zero = {0.f, 0.f, 0.f, 0.f};
    #pragma unroll
    for (int mi = 0; mi < 4; ++mi)
        #pragma unroll
        for (int ni = 0; ni < 2; ++ni) acc[mi][ni] = zero;

    const int NT = K / 32;                              // 32

    // ---- prologue: issue tiles 0 and 1 (3 gloads each) ----
    gload_lds16(gA,               &As[0][32 * w][0]);
    gload_lds16(gA + 16 * K,      &As[0][32 * w + 16][0]);
    gload_lds16(gB,               &Bs[0][16 * w][0]);
    gload_lds16(gA + 32,          &As[1][32 * w][0]);
    gload_lds16(gA + 16 * K + 32, &As[1][32 * w + 16][0]);
    gload_lds16(gB + 32,          &Bs[1][16 * w][0]);
    __builtin_amdgcn_sched_barrier(0);
    asm volatile("s_waitcnt vmcnt(3)" ::: "memory");
    __builtin_amdgcn_s_barrier();
    __builtin_amdgcn_sched_barrier(0);

    int buf = 0;
    for (int t = 0; t < NT; ++t) {
        if (t + 2 < NT) {
            const int nb = (buf + 2 >= 3) ? buf - 1 : buf + 2;
            gload_lds16(gA + (t + 2) * 32,          &As[nb][32 * w][0]);
            gload_lds16(gA + 16 * K + (t + 2) * 32, &As[nb][32 * w + 16][0]);
            gload_lds16(gB + (t + 2) * 32,          &Bs[nb][16 * w][0]);
        }
        bf16x8 af[4], bfr[2];
        #pragma unroll
        for (int mi = 0; mi < 4; ++mi)
            af[mi] = *(const bf16x8*)&As[buf][wm * 64 + mi * 16 + r][g * 8];
        #pragma unroll
        for (int ni = 0; ni < 2; ++ni)
            bfr[ni] = *(const bf16x8*)&Bs[buf][wn * 32 + ni * 16 + r][g * 8];
        #pragma unroll
        for (int mi = 0; mi < 4; ++mi)
            #pragma unroll
            for (int ni = 0; ni < 2; ++ni)
                acc[mi][ni] = __builtin_amdgcn_mfma_f32_16x16x32_bf16(
                    af[mi], bfr[ni], acc[mi][ni], 0, 0, 0);
        if (t + 1 < NT) {
            if (t + 2 < NT) barrier_vm3_lgkm();
            else            barrier_vm0_lgkm();
        }
        buf = (buf + 1 >= 3) ? 0 : buf + 1;
    }

    const int orow = m0 + wm * 64 + g * 4;
    const int ocol = n0 + wn * 32 + r;
    #pragma unroll
    for (int ni = 0; ni < 2; ++ni) {
        const float bb = bias[ocol + ni * 16];
        #pragma unroll
        for (int mi = 0; mi < 4; ++mi) {
            #pragma unroll
            for (int q = 0; q < 4; ++q) {
                float v = fmaxf(acc[mi][ni][q] + bb, 0.f);
                Out[(size_t)(orow + mi * 16 + q) * N + ocol + ni * 16] = (__bf16)v;
            }
        }
    }
}

// ---------------------------------------------------------------------------
// Out-proj GEMM (r13/r14 3-buffer counted-vmcnt — kept byte-identical).
// ---------------------------------------------------------------------------
__global__ __launch_bounds__(512) void gemm_oproj(
    const __bf16* __restrict__ A, const __bf16* __restrict__ BT,
    const float* __restrict__ bias, float* __restrict__ Out,
    int M, int N, int K)
{
    __shared__ __bf16 As[3][128][32];
    __shared__ __bf16 Bs[3][128][32];

    const int tid = threadIdx.x, lane = tid & 63, w = tid >> 6;
    const int wm = w >> 1, wn = w & 1;          // 4 x 2 wave grid
    int bx, by;
    xcd_remap512(blockIdx.x + 8 * blockIdx.y, bx, by);
    const int m0 = by * 128, n0 = bx * 128;
    const int r = lane & 15, g = lane >> 4;

    const int srow = lane >> 2;
    const int scol = (lane & 3) * 8;
    const __bf16* gA = A  + (size_t)(m0 + 16 * w + srow) * K + scol;
    const __bf16* gB = BT + (size_t)(n0 + 16 * w + srow) * K + scol;

    f32x4 acc[2][4];
    const f32x4 zero = {0.f, 0.f, 0.f, 0.f};
    #pragma unroll
    for (int mi = 0; mi < 2; ++mi)
        #pragma unroll
        for (int ni = 0; ni < 4; ++ni) acc[mi][ni] = zero;

    const int NT = K / 32;                              // 16

    gload_lds16(gA,      &As[0][16 * w][0]);
    gload_lds16(gB,      &Bs[0][16 * w][0]);
    gload_lds16(gA + 32, &As[1][16 * w][0]);
    gload_lds16(gB + 32, &Bs[1][16 * w][0]);
    __builtin_amdgcn_sched_barrier(0);
    asm volatile("s_waitcnt vmcnt(2)" ::: "memory");
    __builtin_amdgcn_s_barrier();
    __builtin_amdgcn_sched_barrier(0);

    int buf = 0;
    for (int t = 0; t < NT; ++t) {
        if (t + 2 < NT) {
            const int nb = (buf + 2 >= 3) ? buf - 1 : buf + 2;
            gload_lds16(gA + (t + 2) * 32, &As[nb][16 * w][0]);
            gload_lds16(gB + (t + 2) * 32, &Bs[nb][16 * w][0]);
        }
        bf16x8 af[2], bfr[4];
        #pragma unroll
        for (int mi = 0; mi < 2; ++mi)
            af[mi] = *(const bf16x8*)&As[buf][wm * 32 + mi * 16 + r][g * 8];
        #pragma unroll
        for (int ni = 0; ni < 4; ++ni)
            bfr[ni] = *(const bf16x8*)&Bs[buf][wn * 64 + ni * 16 + r][g * 8];
        #pragma unroll
        for (int mi = 0; mi < 2; ++mi)
            #pragma unroll
            for (int ni = 0; ni < 4; ++ni)
                acc[mi][ni] = __builtin_amdgcn_mfma_f32_16x16x32_bf16(
                    af[mi], bfr[ni], acc[mi][ni], 0, 0, 0);
        if (t + 1 < NT) {
            if (t + 2 < NT) barrier_vm2_lgkm();
            else            barrier_vm0_lgkm();
        }
        buf = (buf + 1 >= 3) ? 0 : buf + 1;
    }

    const int orow = m0 + wm * 32 + g * 4;
    const int ocol = n0 + wn * 64 + r;
    #pragma unroll
    for (int ni = 0; ni < 4; ++ni) {
        const float bb = bias[ocol + ni * 16];
        #pragma unroll
        for (int mi = 0; mi < 2; ++mi) {
            #pragma unroll
            for (int q = 0; q < 4; ++q) {
                Out[(size_t)(orow + mi * 16 + q) * N + ocol + ni * 16]
                    = acc[mi][ni][q] + bb;
            }
        }
    }
}

// ---------------------------------------------------------------------------
// Fused memory attention (MFMA) — at HBM floor (43.7 µs, r8).  Do not touch.
// ---------------------------------------------------------------------------
__device__ __forceinline__ int kbyte(int m, int e) {
    return m * 128 + ((((e >> 3) ^ (m & 7))) << 4) + (e & 7) * 2;
}

__global__ void memory_attn_mfma(
    const __bf16* __restrict__ Q,      // [N][512] bf16 (relu'd q proj)
    const float*  __restrict__ mem,    // [N][128][64] f32
    const __bf16* __restrict__ adrb,   // [128][64] bf16
    __bf16* __restrict__ attn)         // [N][512] bf16
{
    __shared__ __align__(16) unsigned char kbuf[4][4096];
    __shared__ __align__(16) unsigned char tbuf[4][5120];
    __shared__ float denl[4][8];

    const int tid = threadIdx.x, lane = tid & 63, w = tid >> 6;
    const int n = blockIdx.x * 4 + w;
    const int v = lane & 15, g = lane >> 4;

    unsigned char* kb = kbuf[w];
    unsigned char* tb = tbuf[w];

    const __bf16* qp = Q + (size_t)n * 512 + v * 64 + 8 * g;
    const bf16x8 qf0 = *(const bf16x8*)(qp);
    const bf16x8 qf1 = *(const bf16x8*)(qp + 32);

    f32x4 acc[4];
    const f32x4 zero = {0.f, 0.f, 0.f, 0.f};
    #pragma unroll
    for (int nb = 0; nb < 4; ++nb) acc[nb] = zero;
    float psum = 0.f;

    for (int c = 0; c < 4; ++c) {
        const int mb = c * 32;
        #pragma unroll
        for (int i = 0; i < 4; ++i) {
            const int mo = 8 * i + 2 * g;
            const int e  = 4 * v;
            const float* pm = mem + (((size_t)n * 128 + mb + mo) * 64 + e);
            const f32x4 m0 = *(const f32x4*)pm;
            const f32x4 m1 = *(const f32x4*)(pm + 64);
            const bf16x4 a0 = *(const bf16x4*)(adrb + (size_t)(mb + mo) * 64 + e);
            const bf16x4 a1 = *(const bf16x4*)(adrb + (size_t)(mb + mo + 1) * 64 + e);
            bf16x4 k0, k1;
            #pragma unroll
            for (int j = 0; j < 4; ++j) {
                k0[j] = (__bf16)fmaxf(m0[j] + (float)a0[j], 0.f);
                k1[j] = (__bf16)fmaxf(m1[j] + (float)a1[j], 0.f);
            }
            *(bf16x4*)(kb + kbyte(mo,     e)) = k0;
            *(bf16x4*)(kb + kbyte(mo + 1, e)) = k1;
            const int kap = 8 * ((mo >> 2) & 3) + 4 * (mo >> 4) + (mo & 3);
            #pragma unroll
            for (int j2 = 0; j2 < 4; ++j2) {
                bf16x2 p = { (__bf16)m0[j2], (__bf16)m1[j2] };
                *(bf16x2*)(tb + (size_t)(e + j2) * 80 + kap * 2) = p;
            }
        }

        f32x4 sA0 = zero, sA1 = zero;
        {
            const bf16x8 a00 = *(const bf16x8*)(kb + kbyte(v,      8 * g));
            const bf16x8 a01 = *(const bf16x8*)(kb + kbyte(v,      32 + 8 * g));
            const bf16x8 a10 = *(const bf16x8*)(kb + kbyte(v + 16, 8 * g));
            const bf16x8 a11 = *(const bf16x8*)(kb + kbyte(v + 16, 32 + 8 * g));
            sA0 = __builtin_amdgcn_mfma_f32_16x16x32_bf16(a00, qf0, sA0, 0, 0, 0);
            sA0 = __builtin_amdgcn_mfma_f32_16x16x32_bf16(a01, qf1, sA0, 0, 0, 0);
            sA1 = __builtin_amdgcn_mfma_f32_16x16x32_bf16(a10, qf0, sA1, 0, 0, 0);
            sA1 = __builtin_amdgcn_mfma_f32_16x16x32_bf16(a11, qf1, sA1, 0, 0, 0);
        }
        psum += sA0[0] + sA0[1] + sA0[2] + sA0[3]
              + sA1[0] + sA1[1] + sA1[2] + sA1[3];

        bf16x8 pa;
        #pragma unroll
        for (int q = 0; q < 4; ++q) {
            pa[q]     = (__bf16)sA0[q];
            pa[4 + q] = (__bf16)sA1[q];
        }

        #pragma unroll
        for (int nb = 0; nb < 4; ++nb) {
            const bf16x8 bf = *(const bf16x8*)(tb + (size_t)(16 * nb + v) * 80 + 16 * g);
            acc[nb] = __builtin_amdgcn_mfma_f32_16x16x32_bf16(pa, bf, acc[nb], 0, 0, 0);
        }
    }

    psum += __shfl_xor(psum, 16);
    psum += __shfl_xor(psum, 32);
    if (lane < 8) denl[w][lane] = psum;

    if (g < 2) {
        const f32x4 d4 = *(const f32x4*)&denl[w][4 * g];
        float inv[4];
        #pragma unroll
        for (int q = 0; q < 4; ++q) inv[q] = 1.f / (d4[q] + 1e-5f);
        #pragma unroll
        for (int nb = 0; nb < 4; ++nb) {
            #pragma unroll
            for (int q = 0; q < 4; ++q) {
                attn[(size_t)n * 512 + (4 * g + q) * 64 + 16 * nb + v] =
                    (__bf16)(acc[nb][q] * inv[q]);
            }
        }
    }
}

// ---------------------------------------------------------------------------
extern "C" void kernel_launch(void* const* d_in, const int* in_sizes, int n_in,
                              void* d_out, int out_size, void* d_ws, size_t ws_size,
                              hipStream_t stream)
{
    const float* query     = (const float*)d_in[0];
    const float* addresses = (const float*)d_in[1];
    const float* memories  = (const float*)d_in[2];
    const float* Wq        = (const float*)d_in[3];
    const float* bq        = (const float*)d_in[4];
    const float* Wo        = (const float*)d_in[5];
    const float* bo        = (const float*)d_in[6];
    float* out = (float*)d_out;

    char* ws = (char*)d_ws;
    __bf16* WqT  = (__bf16*)(ws);                      // [512][1024]  1 MB
    __bf16* WoT  = (__bf16*)(ws + (1 << 20));          // [1024][512]  1 MB
    __bf16* Qb   = (__bf16*)(ws + (2 << 20));          // [8192][512]  8 MB
    __bf16* Ab   = (__bf16*)(ws + (10 << 20));         // [8192][512]  8 MB
    __bf16* Adrb = (__bf16*)(ws + (18 << 20));         // [128][64]    16 KB
    __bf16* Qbf  = (__bf16*)d_out;                     // [8192][1024] bf16, 16 MB
                                                       // stashed in d_out,
                                                       // overwritten by oproj

    // prep: weight transposes + addr convert + query->bf16 (one launch)
    prep_all<<<5124, 256, 0, stream>>>(Wq, Wo, addresses, query,
                                       WqT, WoT, Adrb, Qbf);

    // Q = relu(Qbf @ Wq + bq) -> bf16 [8192][512]
    // (3-buffer counted vmcnt, 128x64 tiles, 512 blocks = 2/CU)
    gemm_qproj<<<dim3(512 / 64, 8192 / 128), 256, 0, stream>>>(
        Qbf, WqT, bq, Qb, 8192, 512, 1024);

    // fused per-token linear memory read (MFMA) -> attn bf16 [8192][512]
    memory_attn_mfma<<<dim3(8192 / 4), 256, 0, stream>>>(Qb, memories, Adrb, Ab);

    // out = attn @ Wo + bo -> f32 [8192][1024]  (3-buffer counted vmcnt)
    gemm_oproj<<<dim3(1024 / 128, 8192 / 128), 512, 0, stream>>>(
        Ab, WoT, bo, out, 8192, 1024, 512);
}